// Round 5
// baseline (133.371 us; speedup 1.0000x reference)
//
#include <hip/hip_runtime.h>

// SpatialAttention: B=4, C=256, H=W=64 -> N=4096, C_qk=32
// d_out: [output (4*256*4096)] ++ [attention_map (4*4096)]  (fp32)
//
// R2/R3: MFMA structure: S=q.kT (K=32) = one mfma_f32_16x16x32_bf16 per 16x16
// tile; q,kT token-major bf16 (A/B frags = contiguous 16B). Two passes over S
// (rowsums l, then col-means map); gamma==0 => output==x, v/PV paths early-exit.
// R4: vectorized prep (float4 / ushort4), weights converted in-register (no
// wb/wvb staging), projqk grid 1024 + fused v-projection, unroll caps.

#define B_   4
#define C_   256
#define N_   4096
#define CQK_ 32
#define BCN_ (B_*C_*N_)   // 4194304
#define BN_  (B_*N_)      // 16384
#define TP_  68           // LDS transpose tile pitch (ushorts): 8B-aligned rows

typedef __attribute__((ext_vector_type(8))) short short8v;
typedef __attribute__((ext_vector_type(4))) float f32x4;
typedef unsigned short ushort_t;

__device__ __forceinline__ ushort_t f2bf(float f) {
  unsigned u = __builtin_bit_cast(unsigned, f);
  u += 0x7FFFu + ((u >> 16) & 1u);          // round-to-nearest-even
  return (ushort_t)(u >> 16);
}
__device__ __forceinline__ float bf2f(ushort_t h) {
  unsigned u = ((unsigned)h) << 16;
  return __builtin_bit_cast(float, u);
}
// load 8 consecutive fp32 -> bf16 frag
__device__ __forceinline__ short8v ld8f(const float* p) {
  float4 a = *(const float4*)p, b = *(const float4*)(p + 4);
  short8v r;
  r[0]=f2bf(a.x); r[1]=f2bf(a.y); r[2]=f2bf(a.z); r[3]=f2bf(a.w);
  r[4]=f2bf(b.x); r[5]=f2bf(b.y); r[6]=f2bf(b.z); r[7]=f2bf(b.w);
  return r;
}

// ---- prep: out = x (copy), xbt = bf16 token-major transpose of x, + init ----
// grid 1024: b(4) x cg(4) x ng(64); 64ch x 64tok tile via LDS
__global__ __launch_bounds__(256) void
k_prep(const float* __restrict__ x, float* __restrict__ out,
       float* __restrict__ l, ushort_t* __restrict__ xbt) {
  __shared__ ushort_t tile[64 * TP_];
  int blk = blockIdx.x, tid = threadIdx.x;
  int b = blk >> 8, cg = (blk >> 6) & 3, ng = blk & 63;
  int c0 = cg << 6, n0 = ng << 6;
  const float* xb = x + ((size_t)b * C_ + c0) * N_ + n0;
  float* ob = out + ((size_t)b * C_ + c0) * N_ + n0;
#pragma unroll
  for (int it = 0; it < 4; ++it) {
    int flat4 = it * 256 + tid;                  // 1024 float4s
    int r = flat4 >> 4, c4 = flat4 & 15;         // r = ch idx, c4*4 = tok idx
    float4 v = *(const float4*)(xb + (size_t)r * N_ + c4 * 4);
    *(float4*)(ob + (size_t)r * N_ + c4 * 4) = v;
    ushort4 h;
    h.x = f2bf(v.x); h.y = f2bf(v.y); h.z = f2bf(v.z); h.w = f2bf(v.w);
    *(ushort4*)(&tile[r * TP_ + c4 * 4]) = h;
  }
  __syncthreads();
#pragma unroll
  for (int it = 0; it < 4; ++it) {
    int flat4 = it * 256 + tid;
    int nr = flat4 >> 4, cc4 = flat4 & 15;       // nr = tok idx, cc4*4 = ch idx
    ushort4 h;
    h.x = tile[(cc4 * 4 + 0) * TP_ + nr];
    h.y = tile[(cc4 * 4 + 1) * TP_ + nr];
    h.z = tile[(cc4 * 4 + 2) * TP_ + nr];
    h.w = tile[(cc4 * 4 + 3) * TP_ + nr];
    *(ushort4*)(xbt + ((size_t)(b * N_) + n0 + nr) * C_ + c0 + cc4 * 4) = h;
  }
  if (blk < 64) {                                 // zero l + attention_map
    int idx = blk * 256 + tid;
    l[idx] = 0.0f;
    out[BCN_ + idx] = 0.0f;
  }
}

// ---- q/k (+v if gamma!=0) projection via MFMA -------------------------------
// grid 1024: b(4) x ng(256: 16-token groups); wave mt: 0,1->q co0-31; 2,3->k
__global__ __launch_bounds__(256) void
k_projqk(const ushort_t* __restrict__ xbt,
         const float* __restrict__ wq, const float* __restrict__ bq,
         const float* __restrict__ wk, const float* __restrict__ bk,
         const float* __restrict__ wv, const float* __restrict__ bv,
         const float* __restrict__ gamma,
         ushort_t* __restrict__ qb, ushort_t* __restrict__ kb,
         float* __restrict__ v_t) {
  int blk = blockIdx.x;
  int b = blk >> 8, ng = blk & 255;
  int wave = threadIdx.x >> 6, lane = threadIdx.x & 63;
  int col16 = lane & 15, quad = lane >> 4;
  int mt = wave;
  bool isq = mt < 2;
  int co_row = (mt & 1) * 16 + col16;            // A-frag row (out channel)
  const float* wrow = (isq ? wq : wk) + co_row * C_;
  int n = ng * 16 + col16;                        // B-frag row (token)
  const ushort_t* xrow = xbt + ((size_t)(b * N_) + n) * C_;

  short8v bfr[8];
#pragma unroll
  for (int ks = 0; ks < 8; ++ks)
    bfr[ks] = *(const short8v*)(xrow + ks * 32 + quad * 8);

  f32x4 c = {0.f, 0.f, 0.f, 0.f};
#pragma unroll
  for (int ks = 0; ks < 8; ++ks) {
    short8v afr = ld8f(wrow + ks * 32 + quad * 8);
    c = __builtin_amdgcn_mfma_f32_16x16x32_bf16(afr, bfr[ks], c, 0, 0, 0);
  }
  int co_base = (mt & 1) * 16 + quad * 4;        // D row = out channel
  const float* bias = isq ? bq : bk;
  ushort4 pk;
  pk.x = f2bf(c[0] + bias[co_base + 0]); pk.y = f2bf(c[1] + bias[co_base + 1]);
  pk.z = f2bf(c[2] + bias[co_base + 2]); pk.w = f2bf(c[3] + bias[co_base + 3]);
  ushort_t* dst = isq ? qb : kb;
  *(ushort4*)(dst + ((size_t)(b * N_) + n) * CQK_ + co_base) = pk;

  if (gamma[0] != 0.0f) {                         // v projection, 4 mt per wave
    for (int m2 = wave * 4; m2 < wave * 4 + 4; ++m2) {
      f32x4 cv = {0.f, 0.f, 0.f, 0.f};
      const float* wvr = wv + (m2 * 16 + col16) * C_;
#pragma unroll
      for (int ks = 0; ks < 8; ++ks) {
        short8v afr = ld8f(wvr + ks * 32 + quad * 8);
        cv = __builtin_amdgcn_mfma_f32_16x16x32_bf16(afr, bfr[ks], cv, 0, 0, 0);
      }
      int co = m2 * 16 + quad * 4;
      float4 o;
      o.x = cv[0] + bv[co];     o.y = cv[1] + bv[co + 1];
      o.z = cv[2] + bv[co + 2]; o.w = cv[3] + bv[co + 3];
      *(float4*)(v_t + ((size_t)(b * N_) + n) * C_ + co) = o;
    }
  }
}

// ---- pass A: l[b,i] = sum_j exp(S_ij) via MFMA ------------------------------
// grid 1024: b(4) x rg(64: 64-row groups) x js(4: 1024-col splits)
__global__ __launch_bounds__(256) void
k_rowsA(const ushort_t* __restrict__ qb, const ushort_t* __restrict__ kb,
        float* __restrict__ l) {
  int blk = blockIdx.x;
  int b = blk >> 8, rg = (blk >> 2) & 63, js = blk & 3;
  int wave = threadIdx.x >> 6, lane = threadIdx.x & 63;
  int col16 = lane & 15, quad = lane >> 4;
  const ushort_t* qbb = qb + (size_t)b * N_ * CQK_;
  const ushort_t* kbb = kb + (size_t)b * N_ * CQK_;
  int i_base = rg * 64;
  short8v a[4];
#pragma unroll
  for (int t = 0; t < 4; ++t)
    a[t] = *(const short8v*)(qbb + (i_base + t * 16 + col16) * CQK_ + quad * 8);
  float racc[16];
#pragma unroll
  for (int r = 0; r < 16; ++r) racc[r] = 0.0f;
  int j_base = js * 1024 + wave * 256;
#pragma unroll 4
  for (int t = 0; t < 16; ++t) {
    short8v bfr = *(const short8v*)(kbb + (j_base + t * 16 + col16) * CQK_ + quad * 8);
#pragma unroll
    for (int m = 0; m < 4; ++m) {
      f32x4 c = {0.f, 0.f, 0.f, 0.f};
      c = __builtin_amdgcn_mfma_f32_16x16x32_bf16(a[m], bfr, c, 0, 0, 0);
      racc[m * 4 + 0] += __expf(c[0]); racc[m * 4 + 1] += __expf(c[1]);
      racc[m * 4 + 2] += __expf(c[2]); racc[m * 4 + 3] += __expf(c[3]);
    }
  }
#pragma unroll
  for (int r = 0; r < 16; ++r) {              // reduce over cols (lane&15)
    float v = racc[r];
    v += __shfl_xor(v, 1); v += __shfl_xor(v, 2);
    v += __shfl_xor(v, 4); v += __shfl_xor(v, 8);
    racc[r] = v;
  }
  if (col16 == 0) {
    float* lb = l + b * N_ + i_base;
#pragma unroll
    for (int m = 0; m < 4; ++m)
#pragma unroll
      for (int rr = 0; rr < 4; ++rr)
        atomicAdd(&lb[m * 16 + quad * 4 + rr], racc[m * 4 + rr]);
  }
}

// ---- pass B: map[j] = (1/N) sum_i exp(S_ij)/l_i  (S^T tiles: kT rows as A) --
// grid 1024: b(4) x jg(16: 256-col groups) x isp(16: 256-row splits)
__global__ __launch_bounds__(256) void
k_mapB(const ushort_t* __restrict__ qb, const ushort_t* __restrict__ kb,
       const float* __restrict__ l, float* __restrict__ map) {
  int blk = blockIdx.x;
  int b = blk >> 8, jg = (blk >> 4) & 15, isp = blk & 15;
  int wave = threadIdx.x >> 6, lane = threadIdx.x & 63;
  int col16 = lane & 15, quad = lane >> 4;
  const ushort_t* qbb = qb + (size_t)b * N_ * CQK_;
  const ushort_t* kbb = kb + (size_t)b * N_ * CQK_;
  int j_base = jg * 256 + wave * 64;
  short8v a[4];
#pragma unroll
  for (int t = 0; t < 4; ++t)
    a[t] = *(const short8v*)(kbb + (j_base + t * 16 + col16) * CQK_ + quad * 8);
  float csum[16];
#pragma unroll
  for (int r = 0; r < 16; ++r) csum[r] = 0.0f;
  int i_base = isp * 256;
#pragma unroll 4
  for (int t = 0; t < 16; ++t) {
    int i0 = i_base + t * 16;
    short8v bfr = *(const short8v*)(qbb + (i0 + col16) * CQK_ + quad * 8);
    float winv = 1.0f / l[b * N_ + i0 + col16];   // lane's i = i0 + col16
#pragma unroll
    for (int m = 0; m < 4; ++m) {
      f32x4 c = {0.f, 0.f, 0.f, 0.f};
      c = __builtin_amdgcn_mfma_f32_16x16x32_bf16(a[m], bfr, c, 0, 0, 0);
      csum[m * 4 + 0] += __expf(c[0]) * winv; csum[m * 4 + 1] += __expf(c[1]) * winv;
      csum[m * 4 + 2] += __expf(c[2]) * winv; csum[m * 4 + 3] += __expf(c[3]) * winv;
    }
  }
#pragma unroll
  for (int r = 0; r < 16; ++r) {              // reduce over i (lane&15)
    float v = csum[r];
    v += __shfl_xor(v, 1); v += __shfl_xor(v, 2);
    v += __shfl_xor(v, 4); v += __shfl_xor(v, 8);
    csum[r] = v;
  }
  if (col16 == 0) {
    float* mp = map + b * N_ + j_base;
#pragma unroll
    for (int m = 0; m < 4; ++m)
#pragma unroll
      for (int rr = 0; rr < 4; ++rr)
        atomicAdd(&mp[m * 16 + quad * 4 + rr], csum[m * 4 + rr] * (1.0f / (float)N_));
  }
}

// ---- PV + residual add (gamma != 0 only) ------------------------------------
__global__ __launch_bounds__(256) void
k_pv(const ushort_t* __restrict__ qb, const ushort_t* __restrict__ kb,
     const float* __restrict__ v_t, const float* __restrict__ l,
     const float* __restrict__ gamma, float* __restrict__ out) {
  if (gamma[0] == 0.0f) return;
  __shared__ float qs[32 * CQK_];
  __shared__ float invl[32];
  __shared__ float ps[32 * 256];
  int blk = blockIdx.x;
  int b = blk >> 9, i0 = ((blk >> 2) & 127) << 5, jsp = blk & 3;
  int tid = threadIdx.x;
  for (int r = tid; r < 32 * CQK_; r += 256)
    qs[r] = bf2f(qb[((size_t)(b * N_) + i0) * CQK_ + r]);
  if (tid < 32) invl[tid] = 1.0f / l[b * N_ + i0 + tid];
  __syncthreads();
  float g = gamma[0];
  float acc[32];
#pragma unroll
  for (int i = 0; i < 32; ++i) acc[i] = 0.0f;
  for (int jt = jsp * 4; jt < jsp * 4 + 4; ++jt) {
    int j = jt * 256 + tid;
    const ushort_t* krow = kb + ((size_t)(b * N_) + j) * CQK_;
    float kcol[CQK_];
#pragma unroll
    for (int o = 0; o < CQK_; ++o) kcol[o] = bf2f(krow[o]);
#pragma unroll
    for (int i = 0; i < 32; ++i) {
      float s = 0.0f;
#pragma unroll
      for (int o = 0; o < CQK_; ++o) s += qs[i * CQK_ + o] * kcol[o];
      ps[i * 256 + tid] = __expf(s) * invl[i];
    }
    __syncthreads();
    const float* vtb = v_t + ((size_t)(b * N_) + jt * 256) * C_;
    for (int jj = 0; jj < 256; ++jj) {
      float vv = vtb[(size_t)jj * C_ + tid];
#pragma unroll
      for (int i = 0; i < 32; ++i) acc[i] += ps[i * 256 + jj] * vv;
    }
    __syncthreads();
  }
  float* ob = out + ((size_t)(b * C_) + tid) * N_ + i0;
#pragma unroll
  for (int i = 0; i < 32; ++i) atomicAdd(&ob[i], g * acc[i]);
}

extern "C" void kernel_launch(void* const* d_in, const int* in_sizes, int n_in,
                              void* d_out, int out_size, void* d_ws, size_t ws_size,
                              hipStream_t stream) {
  const float* x     = (const float*)d_in[0];
  const float* wq    = (const float*)d_in[1];
  const float* bq    = (const float*)d_in[2];
  const float* wk    = (const float*)d_in[3];
  const float* bk    = (const float*)d_in[4];
  const float* wv    = (const float*)d_in[5];
  const float* bv    = (const float*)d_in[6];
  const float* gamma = (const float*)d_in[7];
  float* out = (float*)d_out;
  float* wsf = (float*)d_ws;
  // ws layout (float offsets):
  float*    l    = wsf;                               // 16384
  ushort_t* xbt  = (ushort_t*)(wsf + 16384);          // 4*4096*256 ush
  ushort_t* qb   = (ushort_t*)(wsf + 2113536);        // 4*4096*32 ush
  ushort_t* kb   = (ushort_t*)(wsf + 2375680);        // 4*4096*32 ush
  float*    v_t  = wsf + 2637824;                     // 4*4096*256 f32 (gamma!=0)

  k_prep  <<<1024, 256, 0, stream>>>(x, out, l, xbt);
  k_projqk<<<1024, 256, 0, stream>>>(xbt, wq, bq, wk, bk, wv, bv, gamma, qb, kb, v_t);
  k_rowsA <<<1024, 256, 0, stream>>>(qb, kb, l);
  k_mapB  <<<1024, 256, 0, stream>>>(qb, kb, l, out + BCN_);
  k_pv    <<<2048, 256, 0, stream>>>(qb, kb, v_t, l, gamma, out);
}

// Round 7
// 122.470 us; speedup vs baseline: 1.0890x; 1.0890x over previous
//
#include <hip/hip_runtime.h>

// SpatialAttention: B=4, C=256, H=W=64 -> N=4096, C_qk=32
// d_out: [output (4*256*4096)] ++ [attention_map (4*4096)]  (fp32)
//
// Structure (R2-R6): S=q.kT (K=32) = one mfma_f32_16x16x32_bf16 per 16x16 tile;
// q,kT token-major bf16. Two passes over S (rowsums l, col-means map).
// gamma==0 (test data) => output==x; v/PV paths early-exit but are implemented.
// R5: prep+projqk fused (xbt eliminated); q pre-scaled by log2(e) so both passes
// use raw v_exp_f32 (2^x); mapB folds -log2(l_i) into the MFMA C-init.
// R6 fix: __builtin_amdgcn_expf -> __builtin_amdgcn_exp2f (2^x is the HW op).

#define B_   4
#define C_   256
#define N_   4096
#define CQK_ 32
#define BCN_ (B_*C_*N_)   // 4194304
#define BN_  (B_*N_)      // 16384
#define TP_  260          // LDS token-row pitch (ushorts); 520B -> conflict-light
#define LOG2E 1.4426950408889634f

typedef __attribute__((ext_vector_type(8))) short short8v;
typedef __attribute__((ext_vector_type(4))) short short4v;
typedef __attribute__((ext_vector_type(4))) float f32x4;
typedef unsigned short ushort_t;

__device__ __forceinline__ ushort_t f2bf(float f) {
  unsigned u = __builtin_bit_cast(unsigned, f);
  u += 0x7FFFu + ((u >> 16) & 1u);          // round-to-nearest-even
  return (ushort_t)(u >> 16);
}
__device__ __forceinline__ float bf2f(ushort_t h) {
  unsigned u = ((unsigned)h) << 16;
  return __builtin_bit_cast(float, u);
}
__device__ __forceinline__ short8v ld8f(const float* p) {   // 8 fp32 -> bf16 frag
  float4 a = *(const float4*)p, b = *(const float4*)(p + 4);
  short8v r;
  r[0]=f2bf(a.x); r[1]=f2bf(a.y); r[2]=f2bf(a.z); r[3]=f2bf(a.w);
  r[4]=f2bf(b.x); r[5]=f2bf(b.y); r[6]=f2bf(b.z); r[7]=f2bf(b.w);
  return r;
}
__device__ __forceinline__ short8v ld8lds(const ushort_t* p) {  // 8B-aligned LDS
  short4v lo = *(const short4v*)p, hi = *(const short4v*)(p + 4);
  return __builtin_shufflevector(lo, hi, 0, 1, 2, 3, 4, 5, 6, 7);
}

// ---- fused prep+proj: out=x, q/k (+v) projections, init l/map ---------------
// grid 512: b(4) x tg(128: 32-token groups). LDS: 32 tokens x 256 ch bf16.
__global__ __launch_bounds__(256) void
k_prep(const float* __restrict__ x,
       const float* __restrict__ wq, const float* __restrict__ bq,
       const float* __restrict__ wk, const float* __restrict__ bk,
       const float* __restrict__ wv, const float* __restrict__ bv,
       const float* __restrict__ gamma,
       float* __restrict__ out, float* __restrict__ l,
       ushort_t* __restrict__ qb, ushort_t* __restrict__ kb,
       float* __restrict__ v_t) {
  __shared__ ushort_t xs[32 * TP_];
  int blk = blockIdx.x, tid = threadIdx.x;
  int b = blk >> 7, n0 = (blk & 127) << 5;
#pragma unroll
  for (int it = 0; it < 8; ++it) {            // stage 256ch x 32tok + out=x
    int flat = it * 256 + tid;                // 2048 float4s
    int c = flat >> 3, t4 = flat & 7;
    size_t off = ((size_t)(b * C_) + c) * N_ + n0 + t4 * 4;
    float4 v = *(const float4*)(x + off);
    *(float4*)(out + off) = v;
    ushort_t* dst = &xs[(t4 * 4) * TP_ + c];
    dst[0]        = f2bf(v.x);
    dst[TP_]      = f2bf(v.y);
    dst[2 * TP_]  = f2bf(v.z);
    dst[3 * TP_]  = f2bf(v.w);
  }
  if (blk < 64) {                             // zero l + attention_map
    int idx = blk * 256 + tid;
    l[idx] = 0.0f;
    out[BCN_ + idx] = 0.0f;
  }
  __syncthreads();

  int wave = tid >> 6, lane = tid & 63;
  int col16 = lane & 15, quad = lane >> 4;
  int g = wave & 1;                           // 16-token group within block
  bool isq = wave < 2;
  int tok_l = g * 16 + col16;
  int n = n0 + tok_l;
  short8v bfr[8];
#pragma unroll
  for (int ks = 0; ks < 8; ++ks)
    bfr[ks] = ld8lds(&xs[tok_l * TP_ + ks * 32 + quad * 8]);

  const float* wrow = isq ? wq : wk;
  const float* bias = isq ? bq : bk;
  ushort_t* dst = isq ? qb : kb;
#pragma unroll
  for (int mt = 0; mt < 2; ++mt) {
    f32x4 c = {0.f, 0.f, 0.f, 0.f};
#pragma unroll
    for (int ks = 0; ks < 8; ++ks) {
      short8v afr = ld8f(wrow + (mt * 16 + col16) * C_ + ks * 32 + quad * 8);
      c = __builtin_amdgcn_mfma_f32_16x16x32_bf16(afr, bfr[ks], c, 0, 0, 0);
    }
    int co = mt * 16 + quad * 4;
    ushort4 pk;
    if (isq) {                                // q pre-scaled by log2(e)
      pk.x = f2bf((c[0] + bias[co + 0]) * LOG2E);
      pk.y = f2bf((c[1] + bias[co + 1]) * LOG2E);
      pk.z = f2bf((c[2] + bias[co + 2]) * LOG2E);
      pk.w = f2bf((c[3] + bias[co + 3]) * LOG2E);
    } else {
      pk.x = f2bf(c[0] + bias[co + 0]); pk.y = f2bf(c[1] + bias[co + 1]);
      pk.z = f2bf(c[2] + bias[co + 2]); pk.w = f2bf(c[3] + bias[co + 3]);
    }
    *(ushort4*)(dst + ((size_t)(b * N_) + n) * CQK_ + co) = pk;
  }

  if (gamma[0] != 0.0f) {                     // v projection (gamma != 0 only)
    int half = wave >> 1;
    for (int vt = 0; vt < 8; ++vt) {
      int tile = half * 8 + vt;
      f32x4 c = {0.f, 0.f, 0.f, 0.f};
#pragma unroll
      for (int ks = 0; ks < 8; ++ks) {
        short8v afr = ld8f(wv + (tile * 16 + col16) * C_ + ks * 32 + quad * 8);
        c = __builtin_amdgcn_mfma_f32_16x16x32_bf16(afr, bfr[ks], c, 0, 0, 0);
      }
      int co = tile * 16 + quad * 4;
      float4 o;
      o.x = c[0] + bv[co];     o.y = c[1] + bv[co + 1];
      o.z = c[2] + bv[co + 2]; o.w = c[3] + bv[co + 3];
      *(float4*)(v_t + ((size_t)(b * N_) + n) * C_ + co) = o;
    }
  }
}

// ---- pass A: l[b,i] = sum_j 2^(S'_ij)  (S' = S*log2e via pre-scaled q) ------
// grid 1024: b(4) x rg(64: 64-row groups) x js(4: 1024-col splits)
__global__ __launch_bounds__(256) void
k_rowsA(const ushort_t* __restrict__ qb, const ushort_t* __restrict__ kb,
        float* __restrict__ l) {
  int blk = blockIdx.x;
  int b = blk >> 8, rg = (blk >> 2) & 63, js = blk & 3;
  int wave = threadIdx.x >> 6, lane = threadIdx.x & 63;
  int col16 = lane & 15, quad = lane >> 4;
  const ushort_t* qbb = qb + (size_t)b * N_ * CQK_;
  const ushort_t* kbb = kb + (size_t)b * N_ * CQK_;
  int i_base = rg * 64;
  short8v a[4];
#pragma unroll
  for (int t = 0; t < 4; ++t)
    a[t] = *(const short8v*)(qbb + (i_base + t * 16 + col16) * CQK_ + quad * 8);
  float racc[16];
#pragma unroll
  for (int r = 0; r < 16; ++r) racc[r] = 0.0f;
  int j_base = js * 1024 + wave * 256;
#pragma unroll 4
  for (int t = 0; t < 16; ++t) {
    short8v bfr = *(const short8v*)(kbb + (j_base + t * 16 + col16) * CQK_ + quad * 8);
#pragma unroll
    for (int m = 0; m < 4; ++m) {
      f32x4 c = {0.f, 0.f, 0.f, 0.f};
      c = __builtin_amdgcn_mfma_f32_16x16x32_bf16(a[m], bfr, c, 0, 0, 0);
      racc[m * 4 + 0] += __builtin_amdgcn_exp2f(c[0]);
      racc[m * 4 + 1] += __builtin_amdgcn_exp2f(c[1]);
      racc[m * 4 + 2] += __builtin_amdgcn_exp2f(c[2]);
      racc[m * 4 + 3] += __builtin_amdgcn_exp2f(c[3]);
    }
  }
#pragma unroll
  for (int r = 0; r < 16; ++r) {              // reduce over cols (lane&15)
    float v = racc[r];
    v += __shfl_xor(v, 1); v += __shfl_xor(v, 2);
    v += __shfl_xor(v, 4); v += __shfl_xor(v, 8);
    racc[r] = v;
  }
  if (col16 == 0) {
    float* lb = l + b * N_ + i_base;
#pragma unroll
    for (int m = 0; m < 4; ++m)
#pragma unroll
      for (int rr = 0; rr < 4; ++rr)
        atomicAdd(&lb[m * 16 + quad * 4 + rr], racc[m * 4 + rr]);
  }
}

// ---- pass B: map[j] = (1/N) sum_i 2^(S'_ij - log2 l_i); C-init = -log2(l) ---
// grid 1024: b(4) x jg(16: 256-col groups) x isp(16: 256-row splits)
__global__ __launch_bounds__(256) void
k_mapB(const ushort_t* __restrict__ qb, const ushort_t* __restrict__ kb,
       const float* __restrict__ l, float* __restrict__ map) {
  int blk = blockIdx.x;
  int b = blk >> 8, jg = (blk >> 4) & 15, isp = blk & 15;
  int wave = threadIdx.x >> 6, lane = threadIdx.x & 63;
  int col16 = lane & 15, quad = lane >> 4;
  const ushort_t* qbb = qb + (size_t)b * N_ * CQK_;
  const ushort_t* kbb = kb + (size_t)b * N_ * CQK_;
  int j_base = jg * 256 + wave * 64;
  short8v a[4];                                // kT rows as A => D = S'^T tile
#pragma unroll
  for (int t = 0; t < 4; ++t)
    a[t] = *(const short8v*)(kbb + (j_base + t * 16 + col16) * CQK_ + quad * 8);
  float csum[16];
#pragma unroll
  for (int r = 0; r < 16; ++r) csum[r] = 0.0f;
  int i_base = isp * 256;
#pragma unroll 4
  for (int t = 0; t < 16; ++t) {
    int i0 = i_base + t * 16;
    short8v bfr = *(const short8v*)(qbb + (i0 + col16) * CQK_ + quad * 8);
    float llog = -__builtin_amdgcn_logf(l[b * N_ + i0 + col16]);  // -log2(l_i)
    f32x4 cinit = {llog, llog, llog, llog};    // D cols = i -> fold 1/l_i here
#pragma unroll
    for (int m = 0; m < 4; ++m) {
      f32x4 c = __builtin_amdgcn_mfma_f32_16x16x32_bf16(a[m], bfr, cinit, 0, 0, 0);
      csum[m * 4 + 0] += __builtin_amdgcn_exp2f(c[0]);
      csum[m * 4 + 1] += __builtin_amdgcn_exp2f(c[1]);
      csum[m * 4 + 2] += __builtin_amdgcn_exp2f(c[2]);
      csum[m * 4 + 3] += __builtin_amdgcn_exp2f(c[3]);
    }
  }
#pragma unroll
  for (int r = 0; r < 16; ++r) {              // reduce over i (lane&15)
    float v = csum[r];
    v += __shfl_xor(v, 1); v += __shfl_xor(v, 2);
    v += __shfl_xor(v, 4); v += __shfl_xor(v, 8);
    csum[r] = v;
  }
  if (col16 == 0) {
    float* mp = map + b * N_ + j_base;
#pragma unroll
    for (int m = 0; m < 4; ++m)
#pragma unroll
      for (int rr = 0; rr < 4; ++rr)
        atomicAdd(&mp[m * 16 + quad * 4 + rr], csum[m * 4 + rr] * (1.0f / (float)N_));
  }
}

// ---- PV + residual add (gamma != 0 only); qb is pre-scaled -> use 2^x -------
__global__ __launch_bounds__(256) void
k_pv(const ushort_t* __restrict__ qb, const ushort_t* __restrict__ kb,
     const float* __restrict__ v_t, const float* __restrict__ l,
     const float* __restrict__ gamma, float* __restrict__ out) {
  if (gamma[0] == 0.0f) return;
  __shared__ float qs[32 * CQK_];
  __shared__ float invl[32];
  __shared__ float ps[32 * 256];
  int blk = blockIdx.x;
  int b = blk >> 9, i0 = ((blk >> 2) & 127) << 5, jsp = blk & 3;
  int tid = threadIdx.x;
  for (int r = tid; r < 32 * CQK_; r += 256)
    qs[r] = bf2f(qb[((size_t)(b * N_) + i0) * CQK_ + r]);
  if (tid < 32) invl[tid] = 1.0f / l[b * N_ + i0 + tid];
  __syncthreads();
  float g = gamma[0];
  float acc[32];
#pragma unroll
  for (int i = 0; i < 32; ++i) acc[i] = 0.0f;
  for (int jt = jsp * 4; jt < jsp * 4 + 4; ++jt) {
    int j = jt * 256 + tid;
    const ushort_t* krow = kb + ((size_t)(b * N_) + j) * CQK_;
    float kcol[CQK_];
#pragma unroll
    for (int o = 0; o < CQK_; ++o) kcol[o] = bf2f(krow[o]);
#pragma unroll
    for (int i = 0; i < 32; ++i) {
      float s = 0.0f;
#pragma unroll
      for (int o = 0; o < CQK_; ++o) s += qs[i * CQK_ + o] * kcol[o];
      ps[i * 256 + tid] = __builtin_amdgcn_exp2f(s) * invl[i];
    }
    __syncthreads();
    const float* vtb = v_t + ((size_t)(b * N_) + jt * 256) * C_;
    for (int jj = 0; jj < 256; ++jj) {
      float vv = vtb[(size_t)jj * C_ + tid];
#pragma unroll
      for (int i = 0; i < 32; ++i) acc[i] += ps[i * 256 + jj] * vv;
    }
    __syncthreads();
  }
  float* ob = out + ((size_t)(b * C_) + tid) * N_ + i0;
#pragma unroll
  for (int i = 0; i < 32; ++i) atomicAdd(&ob[i], g * acc[i]);
}

extern "C" void kernel_launch(void* const* d_in, const int* in_sizes, int n_in,
                              void* d_out, int out_size, void* d_ws, size_t ws_size,
                              hipStream_t stream) {
  const float* x     = (const float*)d_in[0];
  const float* wq    = (const float*)d_in[1];
  const float* bq    = (const float*)d_in[2];
  const float* wk    = (const float*)d_in[3];
  const float* bk    = (const float*)d_in[4];
  const float* wv    = (const float*)d_in[5];
  const float* bv    = (const float*)d_in[6];
  const float* gamma = (const float*)d_in[7];
  float* out = (float*)d_out;
  float* wsf = (float*)d_ws;
  // ws layout (float offsets): l 16384 | qb 262144 | kb 262144 | v_t 4194304
  float*    l   = wsf;
  ushort_t* qb  = (ushort_t*)(wsf + 16384);
  ushort_t* kb  = (ushort_t*)(wsf + 16384 + 262144);
  float*    v_t = wsf + 16384 + 2 * 262144;

  k_prep <<< 512, 256, 0, stream>>>(x, wq, bq, wk, bk, wv, bv, gamma,
                                    out, l, qb, kb, v_t);
  k_rowsA<<<1024, 256, 0, stream>>>(qb, kb, l);
  k_mapB <<<1024, 256, 0, stream>>>(qb, kb, l, out + BCN_);
  k_pv   <<<2048, 256, 0, stream>>>(qb, kb, v_t, l, gamma, out);
}